// Round 1
// 105.104 us; speedup vs baseline: 1.0282x; 1.0282x over previous
//
#include <hip/hip_runtime.h>
#include <hip/hip_bf16.h>

#define BATCH 4
#define SEQ   2048
#define EMB   1024
#define HD    64
#define BT    (BATCH * SEQ)
#define XS_STRIDE 1040   // dword stride 520 = 8 mod 32

// logits scale 1/sqrt(64) folded with log2(e) so softmax can use exp2 directly
#define QSCALE 0.18033688011112042f

typedef __attribute__((ext_vector_type(8))) short bf16x8;
typedef __attribute__((ext_vector_type(4))) float f32x4;

__device__ __forceinline__ ushort f2bf(float f) {   // RTN fp32 -> bf16 bits
    unsigned u = __float_as_uint(f);
    return (ushort)((u + 0x7FFFu + ((u >> 16) & 1u)) >> 16);
}

// ---- prep: Wf = W in MFMA B-fragment order [kc(32)][sub(12)][lane(64)][8] --
// frag element (lane,j): row = sub*16 + (lane&15), e = kc*32 + (lane>>4)*8 + j
__global__ __launch_bounds__(256) void prep(
    const float* __restrict__ Wq, const float* __restrict__ bq,
    const float* __restrict__ Wk, const float* __restrict__ bk,
    const float* __restrict__ Wv, const float* __restrict__ bv,
    ushort* __restrict__ Wf, float* __restrict__ bb)
{
    const int fid = (int)blockIdx.x * 256 + (int)threadIdx.x;   // 0..24575
    const int kc   = fid / 768;
    const int rem  = fid - kc * 768;
    const int sub  = rem >> 6;
    const int lane = rem & 63;
    const int row  = (sub & 3) * 16 + (lane & 15);
    const int e0   = kc * 32 + (lane >> 4) * 8;
    const float* W = (sub < 4) ? Wq : ((sub < 8) ? Wk : Wv);
    const float4 a0 = *(const float4*)(W + (size_t)row * EMB + e0);
    const float4 a1 = *(const float4*)(W + (size_t)row * EMB + e0 + 4);
    bf16x8 w;
    w[0] = (short)f2bf(a0.x); w[1] = (short)f2bf(a0.y);
    w[2] = (short)f2bf(a0.z); w[3] = (short)f2bf(a0.w);
    w[4] = (short)f2bf(a1.x); w[5] = (short)f2bf(a1.y);
    w[6] = (short)f2bf(a1.z); w[7] = (short)f2bf(a1.w);
    *(bf16x8*)(Wf + (size_t)fid * 8) = w;
    if (blockIdx.x == 0 && threadIdx.x < 192) {
        const int i = (int)threadIdx.x;
        const float* B = (i < 64) ? bq : ((i < 128) ? bk : bv);
        bb[i] = B[i & 63];
    }
}

// ---- QKV GEMM v2: 32 rows/block, 8 waves = (sub-triple sg) x (kc-parity kp)
// Each Wf fragment feeds TWO MFMAs (row-groups 0/1) -> Wf L2 traffic halved
// (196->98 MB). K-halved staging: half-1 x loads issued after barrier 1, fly
// under phase-0 compute. kc-parity partials reduced via LDS; kp==0 waves do
// the epilogue. LDS = 66.6K (xs) + 24.6K (red) = 91 KB -> 1 block/CU, 8 waves.
__global__ __launch_bounds__(512, 2) void qkv_gemm(
    const float* __restrict__ x, const ushort* __restrict__ Wf,
    const float* __restrict__ bb,
    ushort* __restrict__ Qf, ushort* __restrict__ Kf, ushort* __restrict__ Vf)
{
    const int t0   = (int)blockIdx.x * 32;
    const int tid  = (int)threadIdx.x;
    const int wv   = tid >> 6;
    const int lane = tid & 63;
    const int col  = lane & 15, quad = lane >> 4;
    const int sg   = wv >> 1;            // sub-triple 0..3
    const int kp   = wv & 1;             // kc parity
    const int sub0 = sg * 3;

    __shared__ ushort xs[32][XS_STRIDE];              // 66.6 KB
    __shared__ __align__(16) float red[4][64][24];    // 24.6 KB

    // ---- stage half 0 (cols 0..511): 32 rows x 512 fp32 -> bf16, coalesced
    float4 v0[8];
    #pragma unroll
    for (int i = 0; i < 8; ++i) {
        const int idx = i * 512 + tid;
        const int row = idx >> 7, c4 = idx & 127;
        v0[i] = *(const float4*)(x + (size_t)(t0 + row) * EMB + c4 * 4);
    }
    #pragma unroll
    for (int i = 0; i < 8; ++i) {
        const int idx = i * 512 + tid;
        const int row = idx >> 7, c4 = idx & 127;
        ushort4 pk;
        pk.x = f2bf(v0[i].x); pk.y = f2bf(v0[i].y);
        pk.z = f2bf(v0[i].z); pk.w = f2bf(v0[i].w);
        *(ushort4*)&xs[row][c4 * 4] = pk;
    }
    __syncthreads();

    // ---- issue half-1 loads now: they complete under phase-0 compute
    float4 v1[8];
    #pragma unroll
    for (int i = 0; i < 8; ++i) {
        const int idx = i * 512 + tid;
        const int row = idx >> 7, c4 = idx & 127;
        v1[i] = *(const float4*)(x + (size_t)(t0 + row) * EMB + 512 + c4 * 4);
    }

    f32x4 acc[2][3];
    #pragma unroll
    for (int rg = 0; rg < 2; ++rg)
        #pragma unroll
        for (int s = 0; s < 3; ++s) acc[rg][s] = (f32x4){0.f, 0.f, 0.f, 0.f};

    // ---- phase 0: kc = kp + 2t (all < 16, reads cols < 512 only)
    #pragma unroll 4
    for (int t = 0; t < 8; ++t) {
        const int kc = kp + 2 * t;
        const bf16x8 a0 = *(const bf16x8*)&xs[col][kc * 32 + quad * 8];
        const bf16x8 a1 = *(const bf16x8*)&xs[16 + col][kc * 32 + quad * 8];
        #pragma unroll
        for (int s = 0; s < 3; ++s) {
            const bf16x8 w = *(const bf16x8*)(Wf + ((size_t)(kc * 12 + sub0 + s) * 64 + lane) * 8);
            acc[0][s] = __builtin_amdgcn_mfma_f32_16x16x32_bf16(a0, w, acc[0][s], 0, 0, 0);
            acc[1][s] = __builtin_amdgcn_mfma_f32_16x16x32_bf16(a1, w, acc[1][s], 0, 0, 0);
        }
    }

    // ---- write half 1 (cols 512..1023: disjoint from phase-0 reads, no race)
    #pragma unroll
    for (int i = 0; i < 8; ++i) {
        const int idx = i * 512 + tid;
        const int row = idx >> 7, c4 = idx & 127;
        ushort4 pk;
        pk.x = f2bf(v1[i].x); pk.y = f2bf(v1[i].y);
        pk.z = f2bf(v1[i].z); pk.w = f2bf(v1[i].w);
        *(ushort4*)&xs[row][512 + c4 * 4] = pk;
    }
    __syncthreads();

    // ---- phase 1: kc = 16 + kp + 2t
    #pragma unroll 4
    for (int t = 0; t < 8; ++t) {
        const int kc = 16 + kp + 2 * t;
        const bf16x8 a0 = *(const bf16x8*)&xs[col][kc * 32 + quad * 8];
        const bf16x8 a1 = *(const bf16x8*)&xs[16 + col][kc * 32 + quad * 8];
        #pragma unroll
        for (int s = 0; s < 3; ++s) {
            const bf16x8 w = *(const bf16x8*)(Wf + ((size_t)(kc * 12 + sub0 + s) * 64 + lane) * 8);
            acc[0][s] = __builtin_amdgcn_mfma_f32_16x16x32_bf16(a0, w, acc[0][s], 0, 0, 0);
            acc[1][s] = __builtin_amdgcn_mfma_f32_16x16x32_bf16(a1, w, acc[1][s], 0, 0, 0);
        }
    }

    // ---- kc-parity reduce: kp=1 waves publish, kp=0 waves sum + epilogue
    if (kp) {
        #pragma unroll
        for (int rg = 0; rg < 2; ++rg)
            #pragma unroll
            for (int s = 0; s < 3; ++s)
                *(f32x4*)&red[sg][lane][(rg * 3 + s) * 4] = acc[rg][s];
    }
    __syncthreads();
    if (kp) return;
    #pragma unroll
    for (int rg = 0; rg < 2; ++rg)
        #pragma unroll
        for (int s = 0; s < 3; ++s)
            acc[rg][s] += *(const f32x4*)&red[sg][lane][(rg * 3 + s) * 4];

    // ---- epilogue: bias + write in fragment order, two 16-row groups
    #pragma unroll
    for (int rg = 0; rg < 2; ++rg) {
        const int tt0 = t0 + rg * 16;
        const int b   = tt0 >> 11;
        const int qt  = (tt0 >> 4) & 127;
        const int sgt = tt0 + quad * 4;               // first of 4 consecutive t/s
        const int itk = (sgt & (SEQ - 1)) >> 6;       // batch-LOCAL K-tile
        #pragma unroll
        for (int s = 0; s < 3; ++s) {
            const int sub  = sub0 + s;
            const int hrow = sub * 16 + col;
            const float bias = bb[hrow];
            if (sub < 4) {                            // Q (scaled)
                const int h = hrow;
                const int f = h >> 5, qd = (h >> 3) & 3, jj = h & 7;
                ushort* base = Qf + (((size_t)(b * 128 + qt) * 2 + f) * 64 + qd * 16 + quad * 4) * 8 + jj;
                #pragma unroll
                for (int i = 0; i < 4; ++i)
                    base[i * 8] = f2bf((acc[rg][s][i] + bias) * QSCALE);
            } else if (sub < 8) {                     // K
                const int h = hrow - 64;
                const int f = h >> 5, qd = (h >> 3) & 3, jj = h & 7;
                const size_t frag = ((size_t)(b * 32 + itk) * 4 + ((sgt >> 4) & 3)) * 2 + f;
                ushort* base = Kf + frag * 512 + ((size_t)((sgt & 15) + 16 * qd)) * 8 + jj;
                #pragma unroll
                for (int i = 0; i < 4; ++i)
                    base[i * 8] = f2bf(acc[rg][s][i] + bias);
            } else {                                  // V (B-frag of PV: n=h, k=s)
                const int h = hrow - 128;
                const int k0 = sgt & 63;
                const int f = k0 >> 5, qd = (k0 >> 3) & 3, j0 = k0 & 7;
                const size_t frag = ((size_t)(b * 32 + itk) * 4 + (h >> 4)) * 2 + f;
                ushort4 pk;
                pk.x = f2bf(acc[rg][s][0] + bias); pk.y = f2bf(acc[rg][s][1] + bias);
                pk.z = f2bf(acc[rg][s][2] + bias); pk.w = f2bf(acc[rg][s][3] + bias);
                *(ushort4*)(Vf + frag * 512 + ((size_t)((h & 15) + 16 * qd)) * 8 + j0) = pk;
            }
        }
    }
}

// ---- attention v2: 256 blocks x 8 waves, 32 Q rows/block (2 16-row tiles)
// Each K/V fragment load now feeds 32 MFMAs (2 Q tiles) instead of 16 ->
// K/V L2 traffic halved (135->68 MB). 8-way K split keeps balance: longest
// block = 32 K-tiles / 8 waves = 4 iters/wave. In-block LDS merge of 8
// partials. LDS = 40K (pt) + 68K (op) + 1K (ll) = 109 KB -> 1 block/CU.
__global__ __launch_bounds__(512, 2) void attn(
    const ushort* __restrict__ Qf, const ushort* __restrict__ Kf,
    const ushort* __restrict__ Vf, float* __restrict__ out)
{
    const int blk  = (int)blockIdx.x;                 // 0..255
    const int b    = blk & 3;
    const int tl   = 63 - (blk >> 2);                 // longest tiles first
    const int t0   = tl * 32;
    const int nt   = ((t0 + 31) >> 6) + 1;            // K-tiles of 64 covering s<=t0+31
    const int tid  = (int)threadIdx.x;
    const int j    = tid >> 6;                        // wave = split index (0..7)
    const int lane = tid & 63;
    const int col  = lane & 15, quad = lane >> 4;

    const ushort* QbA = Qf + ((size_t)(b * 128 + 2 * tl) * 2) * 512;
    const bf16x8 aqA0 = *(const bf16x8*)(QbA + (size_t)lane * 8);
    const bf16x8 aqA1 = *(const bf16x8*)(QbA + 512 + (size_t)lane * 8);
    const bf16x8 aqB0 = *(const bf16x8*)(QbA + 1024 + (size_t)lane * 8);
    const bf16x8 aqB1 = *(const bf16x8*)(QbA + 1536 + (size_t)lane * 8);

    float l_a[4], l_b[4];                             // per-LANE partial sums
    f32x4 o[8];                                       // [0..3]=tileA, [4..7]=tileB
    #pragma unroll
    for (int i = 0; i < 4; ++i) { l_a[i] = 0.f; l_b[i] = 0.f; }
    #pragma unroll
    for (int i = 0; i < 8; ++i) o[i] = (f32x4){0.f, 0.f, 0.f, 0.f};

    __shared__ ushort pt[8][32][80];                  // per-wave P transpose tile
    __shared__ __align__(16) float op[8][32][68];     // per-wave O partial
    __shared__ float ll[8][32];

    // prologue: K fragments for first tile (only if this wave has work)
    bf16x8 kc[4][2];
    if (j < nt) {
        const ushort* Kt = Kf + ((size_t)(b * 32 + j) * 8) * 512;
        #pragma unroll
        for (int sub = 0; sub < 4; ++sub) {
            kc[sub][0] = *(const bf16x8*)(Kt + (size_t)(sub * 2 + 0) * 512 + (size_t)lane * 8);
            kc[sub][1] = *(const bf16x8*)(Kt + (size_t)(sub * 2 + 1) * 512 + (size_t)lane * 8);
        }
    }

    for (int it = j; it < nt; it += 8) {
        const int s0 = it * 64;
        const bool hasNext = (it + 8 < nt);

        // ---- S = (q*scale) . k^T for both Q tiles from current K fragments
        f32x4 scA[4], scB[4];
        #pragma unroll
        for (int sub = 0; sub < 4; ++sub) {
            f32x4 z = {0.f, 0.f, 0.f, 0.f};
            z = __builtin_amdgcn_mfma_f32_16x16x32_bf16(aqA0, kc[sub][0], z, 0, 0, 0);
            z = __builtin_amdgcn_mfma_f32_16x16x32_bf16(aqA1, kc[sub][1], z, 0, 0, 0);
            scA[sub] = z;
            f32x4 y = {0.f, 0.f, 0.f, 0.f};
            y = __builtin_amdgcn_mfma_f32_16x16x32_bf16(aqB0, kc[sub][0], y, 0, 0, 0);
            y = __builtin_amdgcn_mfma_f32_16x16x32_bf16(aqB1, kc[sub][1], y, 0, 0, 0);
            scB[sub] = y;
        }

        // ---- issue V(cur), then K(next) only if a next iter exists
        bf16x8 kn[4][2], vf[4][2];
        {
            const ushort* Vt = Vf + ((size_t)(b * 32 + it) * 8) * 512;
            #pragma unroll
            for (int sub = 0; sub < 4; ++sub) {
                vf[sub][0] = *(const bf16x8*)(Vt + (size_t)(sub * 2 + 0) * 512 + (size_t)lane * 8);
                vf[sub][1] = *(const bf16x8*)(Vt + (size_t)(sub * 2 + 1) * 512 + (size_t)lane * 8);
            }
        }
        if (hasNext) {
            const ushort* Kt = Kf + ((size_t)(b * 32 + it + 8) * 8) * 512;
            #pragma unroll
            for (int sub = 0; sub < 4; ++sub) {
                kn[sub][0] = *(const bf16x8*)(Kt + (size_t)(sub * 2 + 0) * 512 + (size_t)lane * 8);
                kn[sub][1] = *(const bf16x8*)(Kt + (size_t)(sub * 2 + 1) * 512 + (size_t)lane * 8);
            }
        }

        if (it == nt - 1) {                           // only the diagonal tile masks
            #pragma unroll
            for (int sub = 0; sub < 4; ++sub)
                #pragma unroll
                for (int i = 0; i < 4; ++i) {
                    const int s  = s0 + sub * 16 + col;
                    const int tA = t0 + quad * 4 + i;
                    if (s > tA)      scA[sub][i] = -1e30f;   // exp2 -> 0
                    if (s > tA + 16) scB[sub][i] = -1e30f;
                }
        }

        // ---- p = exp2(sc); accumulate l per-lane; stage P for transpose
        #pragma unroll
        for (int sub = 0; sub < 4; ++sub)
            #pragma unroll
            for (int i = 0; i < 4; ++i) {
                const float pA = exp2f(scA[sub][i]);
                l_a[i] += pA;
                pt[j][quad * 4 + i][sub * 16 + col] = f2bf(pA);
                const float pB = exp2f(scB[sub][i]);
                l_b[i] += pB;
                pt[j][16 + quad * 4 + i][sub * 16 + col] = f2bf(pB);
            }

        // ---- P: C/D -> A-operand via LDS (same-wave: waitcnt only, no barrier)
        __asm__ volatile("s_waitcnt lgkmcnt(0)" ::: "memory");
        const bf16x8 apA0 = *(const bf16x8*)&pt[j][col][quad * 8];
        const bf16x8 apA1 = *(const bf16x8*)&pt[j][col][32 + quad * 8];
        const bf16x8 apB0 = *(const bf16x8*)&pt[j][16 + col][quad * 8];
        const bf16x8 apB1 = *(const bf16x8*)&pt[j][16 + col][32 + quad * 8];

        // ---- O += P @ V from prefetched V fragments (shared by both tiles)
        #pragma unroll
        for (int sub = 0; sub < 4; ++sub) {
            o[sub]     = __builtin_amdgcn_mfma_f32_16x16x32_bf16(apA0, vf[sub][0], o[sub], 0, 0, 0);
            o[sub]     = __builtin_amdgcn_mfma_f32_16x16x32_bf16(apA1, vf[sub][1], o[sub], 0, 0, 0);
            o[4 + sub] = __builtin_amdgcn_mfma_f32_16x16x32_bf16(apB0, vf[sub][0], o[4 + sub], 0, 0, 0);
            o[4 + sub] = __builtin_amdgcn_mfma_f32_16x16x32_bf16(apB1, vf[sub][1], o[4 + sub], 0, 0, 0);
        }

        // ---- rotate K
        if (hasNext) {
            #pragma unroll
            for (int sub = 0; sub < 4; ++sub) { kc[sub][0] = kn[sub][0]; kc[sub][1] = kn[sub][1]; }
        }
    }

    // ---- one butterfly for l (sum over the 16 lanes of each quad-row group)
    #pragma unroll
    for (int d = 1; d < 16; d <<= 1)
        #pragma unroll
        for (int i = 0; i < 4; ++i) {
            l_a[i] += __shfl_xor(l_a[i], d, 64);
            l_b[i] += __shfl_xor(l_b[i], d, 64);
        }

    // ---- publish per-wave partial to LDS (waves with no work publish zeros)
    #pragma unroll
    for (int sub = 0; sub < 4; ++sub)
        #pragma unroll
        for (int i = 0; i < 4; ++i) {
            op[j][quad * 4 + i][sub * 16 + col]      = o[sub][i];
            op[j][16 + quad * 4 + i][sub * 16 + col] = o[4 + sub][i];
        }
    if (col == 0) {
        #pragma unroll
        for (int i = 0; i < 4; ++i) {
            ll[j][quad * 4 + i]      = l_a[i];
            ll[j][16 + quad * 4 + i] = l_b[i];
        }
    }
    __syncthreads();

    // ---- merge 8 wave-partials: thread = (row 0..31, 4-col group); direct write
    {
        const int row = tid >> 4, c0 = (tid & 15) * 4;
        float sx = 0.f, sy = 0.f, sz = 0.f, sw = 0.f, ls = 0.f;
        #pragma unroll
        for (int w = 0; w < 8; ++w) {
            const float4 p = *(const float4*)&op[w][row][c0];
            sx += p.x; sy += p.y; sz += p.z; sw += p.w;
            ls += ll[w][row];
        }
        const float rinv = 1.0f / ls;
        float4 res;
        res.x = sx * rinv; res.y = sy * rinv; res.z = sz * rinv; res.w = sw * rinv;
        *(float4*)(out + ((size_t)b * SEQ + t0 + row) * HD + c0) = res;
    }
}

extern "C" void kernel_launch(void* const* d_in, const int* in_sizes, int n_in,
                              void* d_out, int out_size, void* d_ws, size_t ws_size,
                              hipStream_t stream)
{
    const float* x  = (const float*)d_in[0];
    const float* Wq = (const float*)d_in[1];
    const float* bq = (const float*)d_in[2];
    const float* Wk = (const float*)d_in[3];
    const float* bk = (const float*)d_in[4];
    const float* Wv = (const float*)d_in[5];
    const float* bv = (const float*)d_in[6];
    float* out = (float*)d_out;

    char* ws = (char*)d_ws;
    ushort* Wf  = (ushort*)(ws);                        // 384 KB
    float*  bb  = (float*)(ws + 0x60000);               // 768 B
    ushort* Qfb = (ushort*)(ws + 0x61000);              // 1 MB
    ushort* Kfb = (ushort*)(ws + 0x161000);             // 1 MB
    ushort* Vfb = (ushort*)(ws + 0x261000);             // 1 MB

    prep<<<96, 256, 0, stream>>>(Wq, bq, Wk, bk, Wv, bv, Wf, bb);
    qkv_gemm<<<BT / 32, 512, 0, stream>>>(x, Wf, bb, Qfb, Kfb, Vfb);
    attn<<<256, 512, 0, stream>>>(Qfb, Kfb, Vfb, out);
}